// Round 4
// baseline (1103.980 us; speedup 1.0000x reference)
//
#include <hip/hip_runtime.h>
#include <hip/hip_bf16.h>
#include <math.h>

#define N_   32
#define C_   256
#define T_   128
#define V_   25
#define CTV  (C_ * T_ * V_)   // 819200
#define TV   (T_ * V_)        // 3200
#define EPS_ 1e-5f
#define S_Q  0.35355339059327373f

typedef __attribute__((ext_vector_type(8))) short bf16x8;
typedef __attribute__((ext_vector_type(4))) float f32x4;

__device__ inline ushort f2b(float f) {
    __hip_bfloat16 h = __float2bfloat16(f);
    return *reinterpret_cast<ushort*>(&h);
}
__device__ inline float b2f(ushort u) {
    __hip_bfloat16 h;
    *reinterpret_cast<ushort*>(&h) = u;
    return __bfloat162float(h);
}
__device__ inline float tanh_fast(float x) {
    float xc = fminf(fmaxf(x, -12.f), 12.f);
    float e = __expf(xc + xc);
    return (e - 1.f) * __builtin_amdgcn_rcpf(e + 1.f);
}
#define LD8(p) (*(const bf16x8*)(p))
#define MFMA16(a, b, c) __builtin_amdgcn_mfma_f32_16x16x32_bf16(a, b, c, 0, 0, 0)

// ---------------- prep: bf16 weights (q-rows pre-scaled), PE table, zero bins ----
__global__ void prep_kernel(const float* __restrict__ qkv_w,
                            const float* __restrict__ attn_w,
                            ushort* __restrict__ Wq, ushort* __restrict__ Wa,
                            float* __restrict__ pe, float* __restrict__ bins) {
    int idx = blockIdx.x * blockDim.x + threadIdx.x;
    int stride = gridDim.x * blockDim.x;
    for (int i = idx; i < 448 * 256; i += stride) {
        float w = qkv_w[i];
        if (i < 64 * 256) w *= S_Q;          // fold q/pq scale into weight rows 0..63
        Wq[i] = f2b(w);
    }
    for (int i = idx; i < 256 * 256; i += stride) Wa[i] = f2b(attn_w[i]);
    for (int i = idx; i < C_ * V_; i += stride) {
        int c = i / V_, v = i - c * V_;
        int j2 = c & ~1;
        float ang = (float)v * expf(-logf(10000.0f) * (float)j2 / (float)C_);
        pe[i] = (c & 1) ? cosf(ang) : sinf(ang);
    }
    for (int i = idx; i < 512; i += stride) bins[i] = 0.f;
}

// ---------------- data_bn stats: one kernel, lane = fixed joint v ----------------
__global__ __launch_bounds__(1024) void dbn_kernel(const float* __restrict__ x,
                                                   const float* __restrict__ gamma,
                                                   const float* __restrict__ beta,
                                                   float* __restrict__ a_scale,
                                                   float* __restrict__ a_shift) {
    __shared__ float pgS[32][25], pgQ[32][25];
    int c = blockIdx.x;
    int tid = threadIdx.x, g = tid >> 5, l = tid & 31;   // g = n (32 groups)
    float s = 0.f, s2 = 0.f;
    if (l < 25) {
        const float* base = x + (size_t)g * CTV + c * TV + l;
        #pragma unroll 8
        for (int t = 0; t < 128; ++t) {
            float v = base[t * 25];
            s += v; s2 += v * v;
        }
        pgS[g][l] = s; pgQ[g][l] = s2;
    }
    __syncthreads();
    if (tid < 25) {
        float S = 0.f, Q = 0.f;
        #pragma unroll
        for (int g2 = 0; g2 < 32; ++g2) { S += pgS[g2][tid]; Q += pgQ[g2][tid]; }
        float inv = 1.0f / 4096.0f;
        float mean = S * inv, var = Q * inv - mean * mean;
        int f = c * 25 + tid;
        float sc = rsqrtf(var + EPS_) * gamma[f];
        a_scale[f] = sc;
        a_shift[f] = beta[f] - mean * sc;
    }
}

// ---------------- bias2 = Ws*a_shift + b_s ; peproj = Ws*pe + b_s ----------------
__global__ void mkbias_kernel(const ushort* __restrict__ Wq,
                              const float* __restrict__ qkv_b,
                              const float* __restrict__ a_shift,
                              const float* __restrict__ pe,
                              float* __restrict__ bias2, float* __restrict__ peproj) {
    int id = blockIdx.x * 256 + threadIdx.x;
    if (id < 11200) {
        int o = id / 25, v = id - o * 25;
        float acc = qkv_b[o] * (o < 64 ? S_Q : 1.f);
        for (int c = 0; c < 256; ++c)
            acc = fmaf(b2f(Wq[o * 256 + c]), a_shift[c * 25 + v], acc);
        bias2[id] = acc;
    } else if (id < 14400) {
        int id2 = id - 11200;
        int r = id2 / 25, v = id2 - r * 25;
        float acc = qkv_b[r] * (r < 64 ? S_Q : 1.f);
        for (int c = 0; c < 256; ++c)
            acc = fmaf(b2f(Wq[r * 256 + c]), pe[c * 25 + v], acc);
        peproj[id2] = acc;
    }
}

// ---------------- fused per-token kernel ----------------
// qkvT cols: 0..63 q | 64..127 k | 128..191 g | 192..255 pq(=q-w rows) | 256..319 pk
__global__ __launch_bounds__(512, 6) void fused_kernel(
        const float* __restrict__ x,
        const ushort* __restrict__ Wq,
        const float* __restrict__ bias2, const float* __restrict__ peproj,
        const float* __restrict__ a_scale,
        const ushort* __restrict__ Wa, const float* __restrict__ attn_b,
        float* __restrict__ out, float* __restrict__ bins) {
    __shared__ __align__(16) char smem[50176];
    ushort* Bbuf = (ushort*)smem;                 // [32][136] bf16 staging (K-half)
    ushort* qkvT = (ushort*)(smem + 8704);        // [32][328]; later pbuf [8][32][40]
    ushort* qkvV = (ushort*)(smem + 29696);       // [256][40]; later aT [32][264]
    ushort* pbuf = qkvT;
    ushort* aT   = qkvV;
    float*  ybuf = (float*)smem;                  // [256][26] fp32 (front 26.6KB)

    int n = blockIdx.x >> 7, t = blockIdx.x & 127;
    int tid = threadIdx.x, wave = tid >> 6, lane = tid & 63;
    int lr = lane & 15, lg = lane >> 4;
    const float* xp = x + (size_t)n * CTV + t * V_;
    float* outp = out + (size_t)n * CTV + t * V_;
    const f32x4 zacc = {0.f, 0.f, 0.f, 0.f};
    const bf16x8 zero8 = {0, 0, 0, 0, 0, 0, 0, 0};

    int ntile = (wave < 4) ? 4 : 3;
    f32x4 accQ[4][2], accP[2];
    #pragma unroll
    for (int i = 0; i < 4; ++i) { accQ[i][0] = zacc; accQ[i][1] = zacc; }
    accP[0] = zacc; accP[1] = zacc;

    // ================= GEMM1: two K-halves over one staging buffer =================
    #pragma unroll
    for (int kh = 0; kh < 2; ++kh) {
        // stage raw x (bf16)
        for (int i = tid; i < 3200; i += 512) {
            int cc = i / 25, v = i - cc * 25;
            Bbuf[v * 136 + cc] = f2b(xp[(kh * 128 + cc) * TV + v]);
        }
        if (kh == 0)
            for (int i = tid; i < 952; i += 512) Bbuf[3400 + i] = 0;   // rows 25..31
        __syncthreads();
        // pq/pk tile (one per wave): A = Wq rows 0..127
        {
            const ushort* Arow = Wq + (wave * 16 + lr) * 256 + kh * 128;
            #pragma unroll
            for (int kk = 0; kk < 4; ++kk) {
                bf16x8 a  = LD8(Arow + kk * 32 + lg * 8);
                bf16x8 b0 = LD8(Bbuf + lr * 136 + kk * 32 + lg * 8);
                bf16x8 b1 = LD8(Bbuf + (16 + lr) * 136 + kk * 32 + lg * 8);
                accP[0] = MFMA16(a, b0, accP[0]);
                accP[1] = MFMA16(a, b1, accP[1]);
            }
        }
        __syncthreads();
        // in-place transform: raw -> scaled (data-BN scale; shift folded into bias2)
        for (int i = tid; i < 3200; i += 512) {
            int cc = i / 25, v = i - cc * 25;
            int off = v * 136 + cc;
            Bbuf[off] = f2b(b2f(Bbuf[off]) * a_scale[(kh * 128 + cc) * 25 + v]);
        }
        __syncthreads();
        // q/k/g/v tiles
        #pragma unroll
        for (int tt = 0; tt < 4; ++tt) {
            if (tt < ntile) {
                int mt = wave + tt * 8;
                const ushort* Arow = Wq + (mt * 16 + lr) * 256 + kh * 128;
                #pragma unroll
                for (int kk = 0; kk < 4; ++kk) {
                    bf16x8 a  = LD8(Arow + kk * 32 + lg * 8);
                    bf16x8 b0 = LD8(Bbuf + lr * 136 + kk * 32 + lg * 8);
                    bf16x8 b1 = LD8(Bbuf + (16 + lr) * 136 + kk * 32 + lg * 8);
                    accQ[tt][0] = MFMA16(a, b0, accQ[tt][0]);
                    accQ[tt][1] = MFMA16(a, b1, accQ[tt][1]);
                }
            }
        }
        if (kh == 0) __syncthreads();   // protect restage
    }
    // epilogues: pq/pk -> qkvT cols 192..319 (+peproj)
    #pragma unroll
    for (int i2 = 0; i2 < 4; ++i2) {
        int r = wave * 16 + lg * 4 + i2;    // 0..127
        int col = 192 + r;
        qkvT[lr * 328 + col] = f2b(accP[0][i2] + peproj[r * 25 + lr]);
        qkvT[(16 + lr) * 328 + col] =
            (lr < 9) ? f2b(accP[1][i2] + peproj[r * 25 + 16 + lr]) : (ushort)0;
    }
    // q/k/g -> qkvT cols 0..191 ; v -> qkvV row-major (+bias2)
    #pragma unroll
    for (int tt = 0; tt < 4; ++tt) {
        if (tt < ntile) {
            int mt = wave + tt * 8;
            #pragma unroll
            for (int i2 = 0; i2 < 4; ++i2) {
                int o = mt * 16 + lg * 4 + i2;
                float v0 = accQ[tt][0][i2] + bias2[o * 25 + lr];
                float v1 = accQ[tt][1][i2] + ((lr < 9) ? bias2[o * 25 + 16 + lr] : 0.f);
                if (mt < 12) {
                    qkvT[lr * 328 + o] = f2b(v0);
                    qkvT[(16 + lr) * 328 + o] = (lr < 9) ? f2b(v1) : (ushort)0;
                } else {
                    int e = o - 192;
                    qkvV[e * 40 + lr] = f2b(v0);
                    qkvV[e * 40 + 16 + lr] = (lr < 9) ? f2b(v1) : (ushort)0;
                }
            }
        }
    }
    __syncthreads();

    // ================= weights phase (wave = head h) =================
    int h = wave;
    // q-mean via lanes 0..7 + shfl broadcast
    float qs = 0.f;
    if (lane < 8) {
        #pragma unroll
        for (int v = 0; v < 25; ++v) qs += b2f(qkvT[v * 328 + h * 8 + lane]);
        qs *= (1.f / 25.f);
    }
    float m[8];
    #pragma unroll
    for (int d = 0; d < 8; ++d) m[d] = __shfl(qs, d, 64);
    // u1 = mu^T k, u2 = mu^T g for this lane's two w-columns
    float u1a = 0.f, u1b = 0.f, u2a = 0.f, u2b = 0.f;
    #pragma unroll
    for (int d = 0; d < 8; ++d) {
        u1a = fmaf(m[d], b2f(qkvT[lr * 328 + 64 + h * 8 + d]), u1a);
        u1b = fmaf(m[d], b2f(qkvT[(16 + lr) * 328 + 64 + h * 8 + d]), u1b);
        u2a = fmaf(m[d], b2f(qkvT[lr * 328 + 128 + h * 8 + d]), u2a);
        u2b = fmaf(m[d], b2f(qkvT[(16 + lr) * 328 + 128 + h * 8 + d]), u2b);
    }
    // P1 = [q;pq]^T[k;pk], P2 = pq^T pk
    bf16x8 aP1[2], aP2[2], bP1[2], bP2[2];
    #pragma unroll
    for (int mi = 0; mi < 2; ++mi) {
        const ushort* row = qkvT + (mi * 16 + lr) * 328;
        aP1[mi] = (lg == 0) ? LD8(row + h * 8)
                : (lg == 1) ? LD8(row + 192 + h * 8) : zero8;
        aP2[mi] = (lg == 0) ? LD8(row + 192 + h * 8) : zero8;
        bP1[mi] = (lg == 0) ? LD8(row + 64 + h * 8)
                : (lg == 1) ? LD8(row + 256 + h * 8) : zero8;
        bP2[mi] = (lg == 0) ? LD8(row + 256 + h * 8) : zero8;
    }
    f32x4 p1[2][2], p2[2][2];
    #pragma unroll
    for (int mi = 0; mi < 2; ++mi)
        #pragma unroll
        for (int ni = 0; ni < 2; ++ni) {
            p1[mi][ni] = MFMA16(aP1[mi], bP1[ni], zacc);
            p2[mi][ni] = MFMA16(aP2[mi], bP2[ni], zacc);
        }
    __syncthreads();   // all qkvT reads done -> safe to overwrite as pbuf
    #pragma unroll
    for (int mi = 0; mi < 2; ++mi)
        #pragma unroll
        for (int ni = 0; ni < 2; ++ni) {
            float uu1 = ni ? u1b : u1a, uu2 = ni ? u2b : u2a;
            int w = ni * 16 + lr;
            #pragma unroll
            for (int i2 = 0; i2 < 4; ++i2) {
                int v = mi * 16 + lg * 4 + i2;
                float tw = tanh_fast(p1[mi][ni][i2] - uu1) + tanh_fast(p2[mi][ni][i2] + uu2);
                pbuf[(h * 32 + v) * 40 + w] = (w < 25) ? f2b(tw) : (ushort)0;
            }
        }
    __syncthreads();

    // ================= attn = V x weights^T =================
    {
        bf16x8 av[2], bw[2];
        #pragma unroll
        for (int mi = 0; mi < 2; ++mi)
            av[mi] = LD8(qkvV + (h * 32 + mi * 16 + lr) * 40 + lg * 8);
        #pragma unroll
        for (int ni = 0; ni < 2; ++ni)
            bw[ni] = LD8(pbuf + (h * 32 + ni * 16 + lr) * 40 + lg * 8);
        f32x4 at_[2][2];
        #pragma unroll
        for (int mi = 0; mi < 2; ++mi)
            #pragma unroll
            for (int ni = 0; ni < 2; ++ni)
                at_[mi][ni] = MFMA16(av[mi], bw[ni], zacc);
        __syncthreads();   // qkvV/pbuf reads done -> overwrite qkvV region as aT
        #pragma unroll
        for (int mi = 0; mi < 2; ++mi)
            #pragma unroll
            for (int ni = 0; ni < 2; ++ni)
                #pragma unroll
                for (int i2 = 0; i2 < 4; ++i2) {
                    int ge = h * 32 + mi * 16 + lg * 4 + i2;
                    int v = ni * 16 + lr;
                    aT[v * 264 + ge] = (v < 25) ? f2b(at_[mi][ni][i2]) : (ushort)0;
                }
    }
    __syncthreads();

    // ================= GEMM2: attn_w(256x256) x aT^T -> ybuf =================
    #pragma unroll
    for (int tt = 0; tt < 2; ++tt) {
        int mt = wave + tt * 8;
        int o0 = mt * 16;
        const ushort* Arow = Wa + (o0 + lr) * 256;
        f32x4 a0 = zacc, a1 = zacc;
        #pragma unroll
        for (int kk = 0; kk < 8; ++kk) {
            bf16x8 a  = LD8(Arow + kk * 32 + lg * 8);
            bf16x8 b0 = LD8(aT + lr * 264 + kk * 32 + lg * 8);
            bf16x8 b1 = LD8(aT + (16 + lr) * 264 + kk * 32 + lg * 8);
            a0 = MFMA16(a, b0, a0);
            a1 = MFMA16(a, b1, a1);
        }
        #pragma unroll
        for (int i2 = 0; i2 < 4; ++i2) {
            int o = o0 + lg * 4 + i2;
            float bias = attn_b[o];
            ybuf[o * 26 + lr] = a0[i2] + bias;
            if (lr < 9) ybuf[o * 26 + 16 + lr] = a1[i2] + bias;
        }
    }
    __syncthreads();

    // ================= coalesced store + skip + bn2 partial sums =================
    {
        int g = tid >> 5, l = tid & 31;   // 16 groups of 32 lanes
        for (int it = 0; it < 16; ++it) {
            int c = g + it * 16;
            float val = 0.f;
            if (l < 25) {
                val = ybuf[c * 26 + l] + xp[c * TV + l];
                outp[c * TV + l] = val;
            }
            float cs = val, cq = val * val;
            #pragma unroll
            for (int off = 16; off; off >>= 1) {
                cs += __shfl_down(cs, off, 32);
                cq += __shfl_down(cq, off, 32);
            }
            if (l == 0) {
                atomicAdd(&bins[c], cs);
                atomicAdd(&bins[256 + c], cq);
            }
        }
    }
}

// ---------------- bn2 final: scale/shift from bins ----------------
__global__ void bn2_final_kernel(const float* __restrict__ bins,
                                 const float* __restrict__ gamma,
                                 const float* __restrict__ beta,
                                 float* __restrict__ scale,
                                 float* __restrict__ shift) {
    int c = threadIdx.x;
    float inv = 1.0f / (float)(N_ * TV);
    float mean = bins[c] * inv;
    float var = bins[256 + c] * inv - mean * mean;
    float sc = rsqrtf(var + EPS_) * gamma[c];
    scale[c] = sc;
    shift[c] = beta[c] - mean * sc;
}

__global__ void bn2_apply_kernel(float4* __restrict__ y,
                                 const float* __restrict__ scale,
                                 const float* __restrict__ shift) {
    const int total4 = N_ * CTV / 4;
    for (int i = blockIdx.x * blockDim.x + threadIdx.x; i < total4;
         i += gridDim.x * blockDim.x) {
        int c = (i / (TV / 4)) & 255;
        float4 v = y[i];
        float sc = scale[c], sh = shift[c];
        v.x = fmaxf(fmaf(v.x, sc, sh), 0.f);
        v.y = fmaxf(fmaf(v.y, sc, sh), 0.f);
        v.z = fmaxf(fmaf(v.z, sc, sh), 0.f);
        v.w = fmaxf(fmaf(v.w, sc, sh), 0.f);
        y[i] = v;
    }
}

extern "C" void kernel_launch(void* const* d_in, const int* in_sizes, int n_in,
                              void* d_out, int out_size, void* d_ws, size_t ws_size,
                              hipStream_t stream) {
    const float* x      = (const float*)d_in[0];
    const float* qkv_w  = (const float*)d_in[1];
    const float* qkv_b  = (const float*)d_in[2];
    const float* attn_w = (const float*)d_in[3];
    const float* attn_b = (const float*)d_in[4];
    const float* dbn_g  = (const float*)d_in[5];
    const float* dbn_b  = (const float*)d_in[6];
    const float* bn_g   = (const float*)d_in[7];
    const float* bn_b   = (const float*)d_in[8];
    float* out = (float*)d_out;

    char* ws = (char*)d_ws;
    ushort* Wq      = (ushort*)ws;                 // 229376 B
    ushort* Wa      = (ushort*)(ws + 229376);      // 131072 B
    float*  pe      = (float*)(ws + 360448);       // 25600 B
    float*  a_scale = (float*)(ws + 386048);       // 25600 B
    float*  a_shift = (float*)(ws + 411648);       // 25600 B
    float*  bias2   = (float*)(ws + 437248);       // 44800 B
    float*  peproj  = (float*)(ws + 482048);       // 12800 B
    float*  bins    = (float*)(ws + 494848);       // 2048 B
    float*  bn2_sc  = (float*)(ws + 496896);       // 1024 B
    float*  bn2_sh  = (float*)(ws + 497920);       // 1024 B

    prep_kernel<<<256, 256, 0, stream>>>(qkv_w, attn_w, Wq, Wa, pe, bins);
    dbn_kernel<<<C_, 1024, 0, stream>>>(x, dbn_g, dbn_b, a_scale, a_shift);
    mkbias_kernel<<<57, 256, 0, stream>>>(Wq, qkv_b, a_shift, pe, bias2, peproj);
    fused_kernel<<<N_ * T_, 512, 0, stream>>>(x, Wq, bias2, peproj, a_scale,
                                              Wa, attn_b, out, bins);
    bn2_final_kernel<<<1, 256, 0, stream>>>(bins, bn_g, bn_b, bn2_sc, bn2_sh);
    bn2_apply_kernel<<<4096, 256, 0, stream>>>((float4*)out, bn2_sc, bn2_sh);
}

// Round 5
// 696.953 us; speedup vs baseline: 1.5840x; 1.5840x over previous
//
#include <hip/hip_runtime.h>
#include <hip/hip_bf16.h>
#include <math.h>

#define N_   32
#define C_   256
#define T_   128
#define V_   25
#define CTV  (C_ * T_ * V_)   // 819200
#define TV   (T_ * V_)        // 3200
#define EPS_ 1e-5f
#define S_Q  0.35355339059327373f

typedef __attribute__((ext_vector_type(8))) short bf16x8;
typedef __attribute__((ext_vector_type(4))) float f32x4;

__device__ inline ushort f2b(float f) {
    __hip_bfloat16 h = __float2bfloat16(f);
    return *reinterpret_cast<ushort*>(&h);
}
__device__ inline float b2f(ushort u) {
    __hip_bfloat16 h;
    *reinterpret_cast<ushort*>(&h) = u;
    return __bfloat162float(h);
}
__device__ inline float tanh_fast(float x) {
    float xc = fminf(fmaxf(x, -12.f), 12.f);
    float e = __expf(xc + xc);
    return (e - 1.f) * __builtin_amdgcn_rcpf(e + 1.f);
}
#define LD8(p) (*(const bf16x8*)(p))
#define MFMA16(a, b, c) __builtin_amdgcn_mfma_f32_16x16x32_bf16(a, b, c, 0, 0, 0)

// qkvT (swizzled, [32 rows v][320 cols]): cols 0..63 q | 64..127 k | 128..191 g | 192..255 pq | 256..319 pk
__device__ inline int qtswz(int v, int col) {   // ushort index
    return v * 320 + ((((col >> 3)) ^ (v & 7)) << 3) + (col & 7);
}
__device__ inline int qvswz(int e, int w) {     // qkvV swizzled [256][32]
    return e * 32 + (((w >> 3) ^ (e & 3)) << 3) + (w & 7);
}

// ---------------- prep: bf16 weights (q-rows pre-scaled), PE table, zero bins ----
__global__ void prep_kernel(const float* __restrict__ qkv_w,
                            const float* __restrict__ attn_w,
                            ushort* __restrict__ Wq, ushort* __restrict__ Wa,
                            float* __restrict__ pe, float* __restrict__ bins) {
    int idx = blockIdx.x * blockDim.x + threadIdx.x;
    int stride = gridDim.x * blockDim.x;
    for (int i = idx; i < 448 * 256; i += stride) {
        float w = qkv_w[i];
        if (i < 64 * 256) w *= S_Q;
        Wq[i] = f2b(w);
    }
    for (int i = idx; i < 256 * 256; i += stride) Wa[i] = f2b(attn_w[i]);
    for (int i = idx; i < C_ * V_; i += stride) {
        int c = i / V_, v = i - c * V_;
        int j2 = c & ~1;
        float ang = (float)v * expf(-logf(10000.0f) * (float)j2 / (float)C_);
        pe[i] = (c & 1) ? cosf(ang) : sinf(ang);
    }
    for (int i = idx; i < 512; i += stride) bins[i] = 0.f;
}

// ---------------- data_bn stats: one kernel, lane = fixed joint ----------------
__global__ __launch_bounds__(1024) void dbn_kernel(const float* __restrict__ x,
                                                   const float* __restrict__ gamma,
                                                   const float* __restrict__ beta,
                                                   float* __restrict__ a_scale,
                                                   float* __restrict__ a_shift) {
    __shared__ float pgS[32][25], pgQ[32][25];
    int c = blockIdx.x;
    int tid = threadIdx.x, g = tid >> 5, l = tid & 31;
    float s = 0.f, s2 = 0.f;
    if (l < 25) {
        const float* base = x + (size_t)g * CTV + c * TV + l;
        #pragma unroll 8
        for (int t = 0; t < 128; ++t) {
            float v = base[t * 25];
            s += v; s2 += v * v;
        }
        pgS[g][l] = s; pgQ[g][l] = s2;
    }
    __syncthreads();
    if (tid < 25) {
        float S = 0.f, Q = 0.f;
        #pragma unroll
        for (int g2 = 0; g2 < 32; ++g2) { S += pgS[g2][tid]; Q += pgQ[g2][tid]; }
        float inv = 1.0f / 4096.0f;
        float mean = S * inv, var = Q * inv - mean * mean;
        int f = c * 25 + tid;
        float sc = rsqrtf(var + EPS_) * gamma[f];
        a_scale[f] = sc;
        a_shift[f] = beta[f] - mean * sc;
    }
}

// ---------------- bias2 = Ws*a_shift + b_s ; peproj = Ws*pe + b_s ----------------
__global__ void mkbias_kernel(const ushort* __restrict__ Wq,
                              const float* __restrict__ qkv_b,
                              const float* __restrict__ a_shift,
                              const float* __restrict__ pe,
                              float* __restrict__ bias2, float* __restrict__ peproj) {
    int id = blockIdx.x * 256 + threadIdx.x;
    if (id < 11200) {
        int o = id / 25, v = id - o * 25;
        float acc = qkv_b[o] * (o < 64 ? S_Q : 1.f);
        for (int c = 0; c < 256; ++c)
            acc = fmaf(b2f(Wq[o * 256 + c]), a_shift[c * 25 + v], acc);
        bias2[id] = acc;
    } else if (id < 14400) {
        int id2 = id - 11200;
        int r = id2 / 25, v = id2 - r * 25;
        float acc = qkv_b[r] * (r < 64 ? S_Q : 1.f);
        for (int c = 0; c < 256; ++c)
            acc = fmaf(b2f(Wq[r * 256 + c]), pe[c * 25 + v], acc);
        peproj[id2] = acc;
    }
}

// ---------------- fused per-token kernel ----------------
__global__ __launch_bounds__(512, 6) void fused_kernel(
        const float* __restrict__ x,
        const ushort* __restrict__ Wq,
        const float* __restrict__ bias2, const float* __restrict__ peproj,
        const float* __restrict__ a_scale,
        const ushort* __restrict__ Wa, const float* __restrict__ attn_b,
        float* __restrict__ out, float* __restrict__ bins) {
    // Regions: X [0,16896) Braw -> qkvV(swz 16384); Y [16896,33792) Bxn -> aT;
    //          Z [33792,54272) qkvT(swz 20480) -> pbuf [8][32][40]
    __shared__ __align__(16) char smem[54272];
    ushort* Braw = (ushort*)smem;
    ushort* Bxn  = (ushort*)(smem + 16896);
    ushort* qkvT = (ushort*)(smem + 33792);
    ushort* qkvV = (ushort*)smem;
    ushort* aT   = (ushort*)(smem + 16896);
    ushort* pbuf = (ushort*)(smem + 33792);

    int n = blockIdx.x >> 7, t = blockIdx.x & 127;
    int tid = threadIdx.x, wave = tid >> 6, lane = tid & 63;
    int lr = lane & 15, lg = lane >> 4;
    const float* xp = x + (size_t)n * CTV + t * V_;
    float* outp = out + (size_t)n * CTV + t * V_;
    const f32x4 zacc = {0.f, 0.f, 0.f, 0.f};
    const bf16x8 zero8 = {0, 0, 0, 0, 0, 0, 0, 0};

    // ---- stage raw + scaled (shift folded into bias2) ----
    for (int i = tid; i < 6400; i += 512) {
        int c = i / 25, v = i - c * 25;
        float xv = xp[c * TV + v];
        int off = v * 264 + c;
        Braw[off] = f2b(xv);
        Bxn[off]  = f2b(xv * a_scale[i]);
    }
    for (int i = tid; i < 1792; i += 512) {   // zero rows 25..31
        int v = 25 + (i >> 8), c = i & 255;
        int off = v * 264 + c;
        Braw[off] = 0; Bxn[off] = 0;
    }
    __syncthreads();   // B1

    // ---- pq/pk tile (1 per wave), full K, reads Braw ----
    {
        const ushort* Arow = Wq + (wave * 16 + lr) * 256;
        f32x4 a0 = zacc, a1 = zacc;
        #pragma unroll
        for (int kk = 0; kk < 8; ++kk) {
            int k0 = kk * 32 + lg * 8;
            bf16x8 a  = LD8(Arow + k0);
            bf16x8 b0 = LD8(Braw + lr * 264 + k0);
            bf16x8 b1 = LD8(Braw + (16 + lr) * 264 + k0);
            a0 = MFMA16(a, b0, a0);
            a1 = MFMA16(a, b1, a1);
        }
        #pragma unroll
        for (int i2 = 0; i2 < 4; ++i2) {
            int r = wave * 16 + lg * 4 + i2;       // 0..127
            qkvT[qtswz(lr, 192 + r)] = f2b(a0[i2] + peproj[r * 25 + lr]);
            qkvT[qtswz(16 + lr, 192 + r)] =
                (lr < 9) ? f2b(a1[i2] + peproj[r * 25 + 16 + lr]) : (ushort)0;
        }
    }
    __syncthreads();   // B1.5: Braw reads done -> qkvV may overwrite region X

    // ---- q/k/g/v tiles, reads Bxn; immediate epilogues ----
    #pragma unroll
    for (int tt = 0; tt < 4; ++tt) {
        int mt = wave + tt * 8;
        if (mt < 28) {
            const ushort* Arow = Wq + (mt * 16 + lr) * 256;
            f32x4 a0 = zacc, a1 = zacc;
            #pragma unroll
            for (int kk = 0; kk < 8; ++kk) {
                int k0 = kk * 32 + lg * 8;
                bf16x8 a  = LD8(Arow + k0);
                bf16x8 b0 = LD8(Bxn + lr * 264 + k0);
                bf16x8 b1 = LD8(Bxn + (16 + lr) * 264 + k0);
                a0 = MFMA16(a, b0, a0);
                a1 = MFMA16(a, b1, a1);
            }
            #pragma unroll
            for (int i2 = 0; i2 < 4; ++i2) {
                int o = mt * 16 + lg * 4 + i2;
                float v0 = a0[i2] + bias2[o * 25 + lr];
                float v1 = a1[i2] + ((lr < 9) ? bias2[o * 25 + 16 + lr] : 0.f);
                if (mt < 12) {
                    qkvT[qtswz(lr, o)] = f2b(v0);
                    qkvT[qtswz(16 + lr, o)] = (lr < 9) ? f2b(v1) : (ushort)0;
                } else {
                    int e = o - 192;
                    qkvV[qvswz(e, lr)] = f2b(v0);
                    qkvV[qvswz(e, 16 + lr)] = (lr < 9) ? f2b(v1) : (ushort)0;
                }
            }
        }
    }
    __syncthreads();   // B2: all qkvT/qkvV writes + Bxn reads done

    // ---- weights phase (wave = head h) ----
    int h = wave;
    float qs = 0.f;
    if (lane < 8) {
        #pragma unroll
        for (int v = 0; v < 25; ++v)
            qs += b2f(qkvT[v * 320 + ((h ^ (v & 7)) << 3) + lane]);
        qs *= (1.f / 25.f);
    }
    float m[8];
    #pragma unroll
    for (int d = 0; d < 8; ++d) m[d] = __shfl(qs, d, 64);
    float u1a = 0.f, u1b = 0.f, u2a = 0.f, u2b = 0.f;
    {
        int ra = lr, rb = 16 + lr;
        int ka = ((8 + h) ^ (ra & 7)) << 3, kb = ((8 + h) ^ (rb & 7)) << 3;
        int ga = ((16 + h) ^ (ra & 7)) << 3, gb = ((16 + h) ^ (rb & 7)) << 3;
        #pragma unroll
        for (int d = 0; d < 8; ++d) {
            u1a = fmaf(m[d], b2f(qkvT[ra * 320 + ka + d]), u1a);
            u1b = fmaf(m[d], b2f(qkvT[rb * 320 + kb + d]), u1b);
            u2a = fmaf(m[d], b2f(qkvT[ra * 320 + ga + d]), u2a);
            u2b = fmaf(m[d], b2f(qkvT[rb * 320 + gb + d]), u2b);
        }
    }
    bf16x8 aP1[2], aP2[2], bP1[2], bP2[2];
    #pragma unroll
    for (int mi = 0; mi < 2; ++mi) {
        int row = mi * 16 + lr, sx = row & 7;
        const ushort* rp = qkvT + row * 320;
        aP1[mi] = (lg == 0) ? LD8(rp + ((h ^ sx) << 3))
                : (lg == 1) ? LD8(rp + (((24 + h) ^ sx) << 3)) : zero8;
        aP2[mi] = (lg == 0) ? LD8(rp + (((24 + h) ^ sx) << 3)) : zero8;
        bP1[mi] = (lg == 0) ? LD8(rp + (((8 + h) ^ sx) << 3))
                : (lg == 1) ? LD8(rp + (((32 + h) ^ sx) << 3)) : zero8;
        bP2[mi] = (lg == 0) ? LD8(rp + (((32 + h) ^ sx) << 3)) : zero8;
    }
    f32x4 p1[2][2], p2[2][2];
    #pragma unroll
    for (int mi = 0; mi < 2; ++mi)
        #pragma unroll
        for (int ni = 0; ni < 2; ++ni) {
            p1[mi][ni] = MFMA16(aP1[mi], bP1[ni], zacc);
            p2[mi][ni] = MFMA16(aP2[mi], bP2[ni], zacc);
        }
    __syncthreads();   // B3: qkvT reads done -> pbuf may overwrite region Z

    // ---- pbuf[h][v][w] = tanh(P1-u1) + tanh(P2+u2) (wave-local region) ----
    #pragma unroll
    for (int mi = 0; mi < 2; ++mi)
        #pragma unroll
        for (int ni = 0; ni < 2; ++ni) {
            float uu1 = ni ? u1b : u1a, uu2 = ni ? u2b : u2a;
            int w = ni * 16 + lr;
            #pragma unroll
            for (int i2 = 0; i2 < 4; ++i2) {
                int v = mi * 16 + lg * 4 + i2;
                float tw = tanh_fast(p1[mi][ni][i2] - uu1) + tanh_fast(p2[mi][ni][i2] + uu2);
                pbuf[(h * 32 + v) * 40 + w] = (w < 25) ? f2b(tw) : (ushort)0;
            }
        }

    // ---- attn^T: A = weights (M=v,K=w), B = V^T (K=w,N=e); wave-local ----
    {
        bf16x8 aw[2], bv[2];
        #pragma unroll
        for (int mi = 0; mi < 2; ++mi)
            aw[mi] = LD8(pbuf + (h * 32 + mi * 16 + lr) * 40 + lg * 8);
        #pragma unroll
        for (int ni = 0; ni < 2; ++ni) {
            int e = h * 32 + ni * 16 + lr;
            bv[ni] = LD8(qkvV + e * 32 + ((lg ^ (e & 3)) << 3));
        }
        f32x4 at_[2][2];
        #pragma unroll
        for (int mi = 0; mi < 2; ++mi)
            #pragma unroll
            for (int ni = 0; ni < 2; ++ni)
                at_[mi][ni] = MFMA16(aw[mi], bv[ni], zacc);
        // aT (region Y, dead since B2) : aT[v][e]
        #pragma unroll
        for (int mi = 0; mi < 2; ++mi)
            #pragma unroll
            for (int ni = 0; ni < 2; ++ni)
                #pragma unroll
                for (int i2 = 0; i2 < 4; ++i2) {
                    int v = mi * 16 + lg * 4 + i2;
                    int e = h * 32 + ni * 16 + lr;
                    aT[v * 264 + e] = (v < 25) ? f2b(at_[mi][ni][i2]) : (ushort)0;
                }
    }
    __syncthreads();   // B5: aT complete

    // ---- GEMM2 + direct store + fused bn2 partial sums ----
    #pragma unroll
    for (int tt = 0; tt < 2; ++tt) {
        int o0 = (wave + tt * 8) * 16;
        const ushort* Arow = Wa + (o0 + lr) * 256;
        f32x4 a0 = zacc, a1 = zacc;
        #pragma unroll
        for (int kk = 0; kk < 8; ++kk) {
            int k0 = kk * 32 + lg * 8;
            bf16x8 a  = LD8(Arow + k0);
            bf16x8 b0 = LD8(aT + lr * 264 + k0);
            bf16x8 b1 = LD8(aT + (16 + lr) * 264 + k0);
            a0 = MFMA16(a, b0, a0);
            a1 = MFMA16(a, b1, a1);
        }
        #pragma unroll
        for (int i2 = 0; i2 < 4; ++i2) {
            int o = o0 + lg * 4 + i2;
            float bias = attn_b[o];
            float v0 = a0[i2] + bias + xp[o * TV + lr];
            outp[o * TV + lr] = v0;
            float v1 = 0.f;
            if (lr < 9) {
                v1 = a1[i2] + bias + xp[o * TV + 16 + lr];
                outp[o * TV + 16 + lr] = v1;
            }
            float cs = v0 + v1, cq = v0 * v0 + v1 * v1;
            #pragma unroll
            for (int mm = 1; mm < 16; mm <<= 1) {
                cs += __shfl_xor(cs, mm, 64);
                cq += __shfl_xor(cq, mm, 64);
            }
            if (lr == 0) {
                atomicAdd(&bins[o], cs);
                atomicAdd(&bins[256 + o], cq);
            }
        }
    }
}

// ---------------- bn2 final + apply ----------------
__global__ void bn2_final_kernel(const float* __restrict__ bins,
                                 const float* __restrict__ gamma,
                                 const float* __restrict__ beta,
                                 float* __restrict__ scale,
                                 float* __restrict__ shift) {
    int c = threadIdx.x;
    float inv = 1.0f / (float)(N_ * TV);
    float mean = bins[c] * inv;
    float var = bins[256 + c] * inv - mean * mean;
    float sc = rsqrtf(var + EPS_) * gamma[c];
    scale[c] = sc;
    shift[c] = beta[c] - mean * sc;
}

__global__ void bn2_apply_kernel(float4* __restrict__ y,
                                 const float* __restrict__ scale,
                                 const float* __restrict__ shift) {
    const int total4 = N_ * CTV / 4;
    for (int i = blockIdx.x * blockDim.x + threadIdx.x; i < total4;
         i += gridDim.x * blockDim.x) {
        int c = (i / (TV / 4)) & 255;
        float4 v = y[i];
        float sc = scale[c], sh = shift[c];
        v.x = fmaxf(fmaf(v.x, sc, sh), 0.f);
        v.y = fmaxf(fmaf(v.y, sc, sh), 0.f);
        v.z = fmaxf(fmaf(v.z, sc, sh), 0.f);
        v.w = fmaxf(fmaf(v.w, sc, sh), 0.f);
        y[i] = v;
    }
}

extern "C" void kernel_launch(void* const* d_in, const int* in_sizes, int n_in,
                              void* d_out, int out_size, void* d_ws, size_t ws_size,
                              hipStream_t stream) {
    const float* x      = (const float*)d_in[0];
    const float* qkv_w  = (const float*)d_in[1];
    const float* qkv_b  = (const float*)d_in[2];
    const float* attn_w = (const float*)d_in[3];
    const float* attn_b = (const float*)d_in[4];
    const float* dbn_g  = (const float*)d_in[5];
    const float* dbn_b  = (const float*)d_in[6];
    const float* bn_g   = (const float*)d_in[7];
    const float* bn_b   = (const float*)d_in[8];
    float* out = (float*)d_out;

    char* ws = (char*)d_ws;
    ushort* Wq      = (ushort*)ws;                 // 229376 B
    ushort* Wa      = (ushort*)(ws + 229376);      // 131072 B
    float*  pe      = (float*)(ws + 360448);       // 25600 B
    float*  a_scale = (float*)(ws + 386048);       // 25600 B
    float*  a_shift = (float*)(ws + 411648);       // 25600 B
    float*  bias2   = (float*)(ws + 437248);       // 44800 B
    float*  peproj  = (float*)(ws + 482048);       // 12800 B
    float*  bins    = (float*)(ws + 494848);       // 2048 B
    float*  bn2_sc  = (float*)(ws + 496896);       // 1024 B
    float*  bn2_sh  = (float*)(ws + 497920);       // 1024 B

    prep_kernel<<<256, 256, 0, stream>>>(qkv_w, attn_w, Wq, Wa, pe, bins);
    dbn_kernel<<<C_, 1024, 0, stream>>>(x, dbn_g, dbn_b, a_scale, a_shift);
    mkbias_kernel<<<57, 256, 0, stream>>>(Wq, qkv_b, a_shift, pe, bias2, peproj);
    fused_kernel<<<N_ * T_, 512, 0, stream>>>(x, Wq, bias2, peproj, a_scale,
                                              Wa, attn_b, out, bins);
    bn2_final_kernel<<<1, 256, 0, stream>>>(bins, bn_g, bn_b, bn2_sc, bn2_sh);
    bn2_apply_kernel<<<4096, 256, 0, stream>>>((float4*)out, bn2_sc, bn2_sh);
}

// Round 6
// 696.048 us; speedup vs baseline: 1.5861x; 1.0013x over previous
//
#include <hip/hip_runtime.h>
#include <hip/hip_bf16.h>
#include <math.h>

#define N_   32
#define C_   256
#define T_   128
#define V_   25
#define CTV  (C_ * T_ * V_)   // 819200
#define TV   (T_ * V_)        // 3200
#define EPS_ 1e-5f
#define S_Q  0.35355339059327373f

typedef __attribute__((ext_vector_type(8))) short bf16x8;
typedef __attribute__((ext_vector_type(4))) float f32x4;

__device__ inline ushort f2b(float f) {
    __hip_bfloat16 h = __float2bfloat16(f);
    return *reinterpret_cast<ushort*>(&h);
}
__device__ inline float b2f(ushort u) {
    __hip_bfloat16 h;
    *reinterpret_cast<ushort*>(&h) = u;
    return __bfloat162float(h);
}
__device__ inline float tanh_fast(float x) {
    float xc = fminf(fmaxf(x, -12.f), 12.f);
    float e = __expf(xc + xc);
    return (e - 1.f) * __builtin_amdgcn_rcpf(e + 1.f);
}
#define LD8(p) (*(const bf16x8*)(p))
#define MFMA16(a, b, c) __builtin_amdgcn_mfma_f32_16x16x32_bf16(a, b, c, 0, 0, 0)

// qkvT (swizzled, [32 rows v][320 cols]): cols 0..63 q | 64..127 k | 128..191 g | 192..255 pq | 256..319 pk
__device__ inline int qtswz(int v, int col) {   // ushort index
    return v * 320 + ((((col >> 3)) ^ (v & 7)) << 3) + (col & 7);
}
__device__ inline int qvswz(int e, int w) {     // qkvV swizzled [256][32]
    return e * 32 + (((w >> 3) ^ (e & 3)) << 3) + (w & 7);
}

// ---------------- prep: bf16 weights (q-rows pre-scaled), PE table, zero bins ----
__global__ void prep_kernel(const float* __restrict__ qkv_w,
                            const float* __restrict__ attn_w,
                            ushort* __restrict__ Wq, ushort* __restrict__ Wa,
                            float* __restrict__ pe, float* __restrict__ bins) {
    int idx = blockIdx.x * blockDim.x + threadIdx.x;
    int stride = gridDim.x * blockDim.x;
    for (int i = idx; i < 448 * 256; i += stride) {
        float w = qkv_w[i];
        if (i < 64 * 256) w *= S_Q;
        Wq[i] = f2b(w);
    }
    for (int i = idx; i < 256 * 256; i += stride) Wa[i] = f2b(attn_w[i]);
    for (int i = idx; i < C_ * V_; i += stride) {
        int c = i / V_, v = i - c * V_;
        int j2 = c & ~1;
        float ang = (float)v * expf(-logf(10000.0f) * (float)j2 / (float)C_);
        pe[i] = (c & 1) ? cosf(ang) : sinf(ang);
    }
    for (int i = idx; i < 512; i += stride) bins[i] = 0.f;
}

// ---------------- data_bn stats: one kernel, lane = fixed joint ----------------
__global__ __launch_bounds__(1024) void dbn_kernel(const float* __restrict__ x,
                                                   const float* __restrict__ gamma,
                                                   const float* __restrict__ beta,
                                                   float* __restrict__ a_scale,
                                                   float* __restrict__ a_shift) {
    __shared__ float pgS[32][25], pgQ[32][25];
    int c = blockIdx.x;
    int tid = threadIdx.x, g = tid >> 5, l = tid & 31;
    float s = 0.f, s2 = 0.f;
    if (l < 25) {
        const float* base = x + (size_t)g * CTV + c * TV + l;
        #pragma unroll 8
        for (int t = 0; t < 128; ++t) {
            float v = base[t * 25];
            s += v; s2 += v * v;
        }
        pgS[g][l] = s; pgQ[g][l] = s2;
    }
    __syncthreads();
    if (tid < 25) {
        float S = 0.f, Q = 0.f;
        #pragma unroll
        for (int g2 = 0; g2 < 32; ++g2) { S += pgS[g2][tid]; Q += pgQ[g2][tid]; }
        float inv = 1.0f / 4096.0f;
        float mean = S * inv, var = Q * inv - mean * mean;
        int f = c * 25 + tid;
        float sc = rsqrtf(var + EPS_) * gamma[f];
        a_scale[f] = sc;
        a_shift[f] = beta[f] - mean * sc;
    }
}

// ---------------- bias2 = Ws*a_shift + b_s ; peproj = Ws*pe + b_s ----------------
__global__ void mkbias_kernel(const ushort* __restrict__ Wq,
                              const float* __restrict__ qkv_b,
                              const float* __restrict__ a_shift,
                              const float* __restrict__ pe,
                              float* __restrict__ bias2, float* __restrict__ peproj) {
    int id = blockIdx.x * 256 + threadIdx.x;
    if (id < 11200) {
        int o = id / 25, v = id - o * 25;
        float acc = qkv_b[o] * (o < 64 ? S_Q : 1.f);
        for (int c = 0; c < 256; ++c)
            acc = fmaf(b2f(Wq[o * 256 + c]), a_shift[c * 25 + v], acc);
        bias2[id] = acc;
    } else if (id < 14400) {
        int id2 = id - 11200;
        int r = id2 / 25, v = id2 - r * 25;
        float acc = qkv_b[r] * (r < 64 ? S_Q : 1.f);
        for (int c = 0; c < 256; ++c)
            acc = fmaf(b2f(Wq[r * 256 + c]), pe[c * 25 + v], acc);
        peproj[id2] = acc;
    }
}

// ---------------- fused per-token kernel ----------------
__global__ __launch_bounds__(512, 4) void fused_kernel(
        const float* __restrict__ x,
        const ushort* __restrict__ Wq,
        const float* __restrict__ bias2, const float* __restrict__ peproj,
        const float* __restrict__ a_scale,
        const ushort* __restrict__ Wa, const float* __restrict__ attn_b,
        float* __restrict__ out, float* __restrict__ bins) {
    // Regions: X [0,16896) Braw -> qkvV(swz 16384); Y [16896,33792) Bxn -> aT;
    //          Z [33792,54272) qkvT(swz 20480) -> pbuf [8][32][40]
    __shared__ __align__(16) char smem[54272];
    ushort* Braw = (ushort*)smem;
    ushort* Bxn  = (ushort*)(smem + 16896);
    ushort* qkvT = (ushort*)(smem + 33792);
    ushort* qkvV = (ushort*)smem;
    ushort* aT   = (ushort*)(smem + 16896);
    ushort* pbuf = (ushort*)(smem + 33792);

    int n = blockIdx.x >> 7, t = blockIdx.x & 127;
    int tid = threadIdx.x, wave = tid >> 6, lane = tid & 63;
    int lr = lane & 15, lg = lane >> 4;
    const float* xp = x + (size_t)n * CTV + t * V_;
    float* outp = out + (size_t)n * CTV + t * V_;
    const f32x4 zacc = {0.f, 0.f, 0.f, 0.f};
    const bf16x8 zero8 = {0, 0, 0, 0, 0, 0, 0, 0};

    // ---- stage raw + scaled (shift folded into bias2) ----
    for (int i = tid; i < 6400; i += 512) {
        int c = i / 25, v = i - c * 25;
        float xv = xp[c * TV + v];
        int off = v * 264 + c;
        Braw[off] = f2b(xv);
        Bxn[off]  = f2b(xv * a_scale[i]);
    }
    for (int i = tid; i < 1792; i += 512) {   // zero rows 25..31
        int v = 25 + (i >> 8), c = i & 255;
        int off = v * 264 + c;
        Braw[off] = 0; Bxn[off] = 0;
    }
    __syncthreads();   // B1

    // ---- pq/pk tile (1 per wave), full K, reads Braw ----
    {
        const ushort* Arow = Wq + (wave * 16 + lr) * 256;
        f32x4 a0 = zacc, a1 = zacc;
        #pragma unroll
        for (int kk = 0; kk < 8; ++kk) {
            int k0 = kk * 32 + lg * 8;
            bf16x8 a  = LD8(Arow + k0);
            bf16x8 b0 = LD8(Braw + lr * 264 + k0);
            bf16x8 b1 = LD8(Braw + (16 + lr) * 264 + k0);
            a0 = MFMA16(a, b0, a0);
            a1 = MFMA16(a, b1, a1);
        }
        #pragma unroll
        for (int i2 = 0; i2 < 4; ++i2) {
            int r = wave * 16 + lg * 4 + i2;       // 0..127
            qkvT[qtswz(lr, 192 + r)] = f2b(a0[i2] + peproj[r * 25 + lr]);
            qkvT[qtswz(16 + lr, 192 + r)] =
                (lr < 9) ? f2b(a1[i2] + peproj[r * 25 + 16 + lr]) : (ushort)0;
        }
    }
    __syncthreads();   // B1.5: Braw reads done -> qkvV may overwrite region X

    // ---- q/k/g/v tiles: kk-outer, shared B fragments across the wave's tiles ----
    {
        int myTiles = (wave < 4) ? 4 : 3;   // tiles mt = wave + tt*8, mt < 28
        f32x4 acc[4][2];
        #pragma unroll
        for (int i = 0; i < 4; ++i) { acc[i][0] = zacc; acc[i][1] = zacc; }
        #pragma unroll
        for (int kk = 0; kk < 8; ++kk) {
            int k0 = kk * 32 + lg * 8;
            bf16x8 b0 = LD8(Bxn + lr * 264 + k0);
            bf16x8 b1 = LD8(Bxn + (16 + lr) * 264 + k0);
            #pragma unroll
            for (int tt = 0; tt < 4; ++tt) {
                if (tt < myTiles) {
                    int mt = wave + tt * 8;
                    bf16x8 a = LD8(Wq + (mt * 16 + lr) * 256 + k0);
                    acc[tt][0] = MFMA16(a, b0, acc[tt][0]);
                    acc[tt][1] = MFMA16(a, b1, acc[tt][1]);
                }
            }
        }
        #pragma unroll
        for (int tt = 0; tt < 4; ++tt) {
            if (tt < myTiles) {
                int mt = wave + tt * 8;
                #pragma unroll
                for (int i2 = 0; i2 < 4; ++i2) {
                    int o = mt * 16 + lg * 4 + i2;
                    float v0 = acc[tt][0][i2] + bias2[o * 25 + lr];
                    float v1 = acc[tt][1][i2] + ((lr < 9) ? bias2[o * 25 + 16 + lr] : 0.f);
                    if (mt < 12) {
                        qkvT[qtswz(lr, o)] = f2b(v0);
                        qkvT[qtswz(16 + lr, o)] = (lr < 9) ? f2b(v1) : (ushort)0;
                    } else {
                        int e = o - 192;
                        qkvV[qvswz(e, lr)] = f2b(v0);
                        qkvV[qvswz(e, 16 + lr)] = (lr < 9) ? f2b(v1) : (ushort)0;
                    }
                }
            }
        }
    }
    __syncthreads();   // B2: all qkvT/qkvV writes + Bxn reads done

    // ---- weights phase (wave = head h) ----
    int h = wave;
    float qs = 0.f;
    if (lane < 8) {
        #pragma unroll
        for (int v = 0; v < 25; ++v)
            qs += b2f(qkvT[v * 320 + ((h ^ (v & 7)) << 3) + lane]);
        qs *= (1.f / 25.f);
    }
    float m[8];
    #pragma unroll
    for (int d = 0; d < 8; ++d) m[d] = __shfl(qs, d, 64);
    float u1a = 0.f, u1b = 0.f, u2a = 0.f, u2b = 0.f;
    {
        int ra = lr, rb = 16 + lr;
        int ka = ((8 + h) ^ (ra & 7)) << 3, kb = ((8 + h) ^ (rb & 7)) << 3;
        int ga = ((16 + h) ^ (ra & 7)) << 3, gb = ((16 + h) ^ (rb & 7)) << 3;
        #pragma unroll
        for (int d = 0; d < 8; ++d) {
            u1a = fmaf(m[d], b2f(qkvT[ra * 320 + ka + d]), u1a);
            u1b = fmaf(m[d], b2f(qkvT[rb * 320 + kb + d]), u1b);
            u2a = fmaf(m[d], b2f(qkvT[ra * 320 + ga + d]), u2a);
            u2b = fmaf(m[d], b2f(qkvT[rb * 320 + gb + d]), u2b);
        }
    }
    bf16x8 aP1[2], aP2[2], bP1[2], bP2[2];
    #pragma unroll
    for (int mi = 0; mi < 2; ++mi) {
        int row = mi * 16 + lr, sx = row & 7;
        const ushort* rp = qkvT + row * 320;
        aP1[mi] = (lg == 0) ? LD8(rp + ((h ^ sx) << 3))
                : (lg == 1) ? LD8(rp + (((24 + h) ^ sx) << 3)) : zero8;
        aP2[mi] = (lg == 0) ? LD8(rp + (((24 + h) ^ sx) << 3)) : zero8;
        bP1[mi] = (lg == 0) ? LD8(rp + (((8 + h) ^ sx) << 3))
                : (lg == 1) ? LD8(rp + (((32 + h) ^ sx) << 3)) : zero8;
        bP2[mi] = (lg == 0) ? LD8(rp + (((32 + h) ^ sx) << 3)) : zero8;
    }
    f32x4 p1[2][2], p2[2][2];
    #pragma unroll
    for (int mi = 0; mi < 2; ++mi)
        #pragma unroll
        for (int ni = 0; ni < 2; ++ni) {
            p1[mi][ni] = MFMA16(aP1[mi], bP1[ni], zacc);
            p2[mi][ni] = MFMA16(aP2[mi], bP2[ni], zacc);
        }
    __syncthreads();   // B3: qkvT reads done -> pbuf may overwrite region Z

    // ---- pbuf[h][v][w] = tanh(P1-u1) + tanh(P2+u2) (wave-local region) ----
    #pragma unroll
    for (int mi = 0; mi < 2; ++mi)
        #pragma unroll
        for (int ni = 0; ni < 2; ++ni) {
            float uu1 = ni ? u1b : u1a, uu2 = ni ? u2b : u2a;
            int w = ni * 16 + lr;
            #pragma unroll
            for (int i2 = 0; i2 < 4; ++i2) {
                int v = mi * 16 + lg * 4 + i2;
                float tw = tanh_fast(p1[mi][ni][i2] - uu1) + tanh_fast(p2[mi][ni][i2] + uu2);
                pbuf[(h * 32 + v) * 40 + w] = (w < 25) ? f2b(tw) : (ushort)0;
            }
        }

    // ---- attn^T: A = weights (M=v,K=w), B = V^T (K=w,N=e); wave-local ----
    {
        bf16x8 aw[2], bv[2];
        #pragma unroll
        for (int mi = 0; mi < 2; ++mi)
            aw[mi] = LD8(pbuf + (h * 32 + mi * 16 + lr) * 40 + lg * 8);
        #pragma unroll
        for (int ni = 0; ni < 2; ++ni) {
            int e = h * 32 + ni * 16 + lr;
            bv[ni] = LD8(qkvV + e * 32 + ((lg ^ (e & 3)) << 3));
        }
        f32x4 at_[2][2];
        #pragma unroll
        for (int mi = 0; mi < 2; ++mi)
            #pragma unroll
            for (int ni = 0; ni < 2; ++ni)
                at_[mi][ni] = MFMA16(aw[mi], bv[ni], zacc);
        // aT (region Y, dead since B2) : aT[v][e]
        #pragma unroll
        for (int mi = 0; mi < 2; ++mi)
            #pragma unroll
            for (int ni = 0; ni < 2; ++ni)
                #pragma unroll
                for (int i2 = 0; i2 < 4; ++i2) {
                    int v = mi * 16 + lg * 4 + i2;
                    int e = h * 32 + ni * 16 + lr;
                    aT[v * 264 + e] = (v < 25) ? f2b(at_[mi][ni][i2]) : (ushort)0;
                }
    }
    __syncthreads();   // B5: aT complete

    // ---- GEMM2 + direct store + fused bn2 partial sums ----
    #pragma unroll
    for (int tt = 0; tt < 2; ++tt) {
        int o0 = (wave + tt * 8) * 16;
        const ushort* Arow = Wa + (o0 + lr) * 256;
        f32x4 a0 = zacc, a1 = zacc;
        #pragma unroll
        for (int kk = 0; kk < 8; ++kk) {
            int k0 = kk * 32 + lg * 8;
            bf16x8 a  = LD8(Arow + k0);
            bf16x8 b0 = LD8(aT + lr * 264 + k0);
            bf16x8 b1 = LD8(aT + (16 + lr) * 264 + k0);
            a0 = MFMA16(a, b0, a0);
            a1 = MFMA16(a, b1, a1);
        }
        #pragma unroll
        for (int i2 = 0; i2 < 4; ++i2) {
            int o = o0 + lg * 4 + i2;
            float bias = attn_b[o];
            float v0 = a0[i2] + bias + xp[o * TV + lr];
            outp[o * TV + lr] = v0;
            float v1 = 0.f;
            if (lr < 9) {
                v1 = a1[i2] + bias + xp[o * TV + 16 + lr];
                outp[o * TV + 16 + lr] = v1;
            }
            float cs = v0 + v1, cq = v0 * v0 + v1 * v1;
            #pragma unroll
            for (int mm = 1; mm < 16; mm <<= 1) {
                cs += __shfl_xor(cs, mm, 64);
                cq += __shfl_xor(cq, mm, 64);
            }
            if (lr == 0) {
                atomicAdd(&bins[o], cs);
                atomicAdd(&bins[256 + o], cq);
            }
        }
    }
}

// ---------------- bn2 final + apply ----------------
__global__ void bn2_final_kernel(const float* __restrict__ bins,
                                 const float* __restrict__ gamma,
                                 const float* __restrict__ beta,
                                 float* __restrict__ scale,
                                 float* __restrict__ shift) {
    int c = threadIdx.x;
    float inv = 1.0f / (float)(N_ * TV);
    float mean = bins[c] * inv;
    float var = bins[256 + c] * inv - mean * mean;
    float sc = rsqrtf(var + EPS_) * gamma[c];
    scale[c] = sc;
    shift[c] = beta[c] - mean * sc;
}

__global__ void bn2_apply_kernel(float4* __restrict__ y,
                                 const float* __restrict__ scale,
                                 const float* __restrict__ shift) {
    const int total4 = N_ * CTV / 4;
    for (int i = blockIdx.x * blockDim.x + threadIdx.x; i < total4;
         i += gridDim.x * blockDim.x) {
        int c = (i / (TV / 4)) & 255;
        float4 v = y[i];
        float sc = scale[c], sh = shift[c];
        v.x = fmaxf(fmaf(v.x, sc, sh), 0.f);
        v.y = fmaxf(fmaf(v.y, sc, sh), 0.f);
        v.z = fmaxf(fmaf(v.z, sc, sh), 0.f);
        v.w = fmaxf(fmaf(v.w, sc, sh), 0.f);
        y[i] = v;
    }
}

extern "C" void kernel_launch(void* const* d_in, const int* in_sizes, int n_in,
                              void* d_out, int out_size, void* d_ws, size_t ws_size,
                              hipStream_t stream) {
    const float* x      = (const float*)d_in[0];
    const float* qkv_w  = (const float*)d_in[1];
    const float* qkv_b  = (const float*)d_in[2];
    const float* attn_w = (const float*)d_in[3];
    const float* attn_b = (const float*)d_in[4];
    const float* dbn_g  = (const float*)d_in[5];
    const float* dbn_b  = (const float*)d_in[6];
    const float* bn_g   = (const float*)d_in[7];
    const float* bn_b   = (const float*)d_in[8];
    float* out = (float*)d_out;

    char* ws = (char*)d_ws;
    ushort* Wq      = (ushort*)ws;                 // 229376 B
    ushort* Wa      = (ushort*)(ws + 229376);      // 131072 B
    float*  pe      = (float*)(ws + 360448);       // 25600 B
    float*  a_scale = (float*)(ws + 386048);       // 25600 B
    float*  a_shift = (float*)(ws + 411648);       // 25600 B
    float*  bias2   = (float*)(ws + 437248);       // 44800 B
    float*  peproj  = (float*)(ws + 482048);       // 12800 B
    float*  bins    = (float*)(ws + 494848);       // 2048 B
    float*  bn2_sc  = (float*)(ws + 496896);       // 1024 B
    float*  bn2_sh  = (float*)(ws + 497920);       // 1024 B

    prep_kernel<<<256, 256, 0, stream>>>(qkv_w, attn_w, Wq, Wa, pe, bins);
    dbn_kernel<<<C_, 1024, 0, stream>>>(x, dbn_g, dbn_b, a_scale, a_shift);
    mkbias_kernel<<<57, 256, 0, stream>>>(Wq, qkv_b, a_shift, pe, bias2, peproj);
    fused_kernel<<<N_ * T_, 512, 0, stream>>>(x, Wq, bias2, peproj, a_scale,
                                              Wa, attn_b, out, bins);
    bn2_final_kernel<<<1, 256, 0, stream>>>(bins, bn_g, bn_b, bn2_sc, bn2_sh);
    bn2_apply_kernel<<<4096, 256, 0, stream>>>((float4*)out, bn2_sc, bn2_sh);
}

// Round 7
// 374.654 us; speedup vs baseline: 2.9467x; 1.8578x over previous
//
#include <hip/hip_runtime.h>
#include <hip/hip_bf16.h>
#include <math.h>

#define N_   32
#define C_   256
#define T_   128
#define V_   25
#define CTV  (C_ * T_ * V_)   // 819200
#define TV   (T_ * V_)        // 3200
#define EPS_ 1e-5f
#define S_Q  0.35355339059327373f
#define NCOPY 64              // bn2 partial-sum copies (atomic chain depth 4096/NCOPY)

typedef __attribute__((ext_vector_type(8))) short bf16x8;
typedef __attribute__((ext_vector_type(4))) float f32x4;

__device__ inline ushort f2b(float f) {
    __hip_bfloat16 h = __float2bfloat16(f);
    return *reinterpret_cast<ushort*>(&h);
}
__device__ inline float b2f(ushort u) {
    __hip_bfloat16 h;
    *reinterpret_cast<ushort*>(&h) = u;
    return __bfloat162float(h);
}
__device__ inline float tanh_fast(float x) {
    float xc = fminf(fmaxf(x, -12.f), 12.f);
    float e = __expf(xc + xc);
    return (e - 1.f) * __builtin_amdgcn_rcpf(e + 1.f);
}
#define LD8(p) (*(const bf16x8*)(p))
#define MFMA16(a, b, c) __builtin_amdgcn_mfma_f32_16x16x32_bf16(a, b, c, 0, 0, 0)

// qkvT (swizzled, [32 rows v][320 cols]): cols 0..63 q | 64..127 k | 128..191 g | 192..255 pq | 256..319 pk
__device__ inline int qtswz(int v, int col) {   // ushort index
    return v * 320 + ((((col >> 3)) ^ (v & 7)) << 3) + (col & 7);
}
__device__ inline int qvswz(int e, int w) {     // qkvV swizzled [256][32]
    return e * 32 + (((w >> 3) ^ (e & 3)) << 3) + (w & 7);
}

// ---------------- prep: bf16 weights (q-rows pre-scaled), PE table, zero bins ----
__global__ void prep_kernel(const float* __restrict__ qkv_w,
                            const float* __restrict__ attn_w,
                            ushort* __restrict__ Wq, ushort* __restrict__ Wa,
                            float* __restrict__ pe, float* __restrict__ bins) {
    int idx = blockIdx.x * blockDim.x + threadIdx.x;
    int stride = gridDim.x * blockDim.x;
    for (int i = idx; i < 448 * 256; i += stride) {
        float w = qkv_w[i];
        if (i < 64 * 256) w *= S_Q;
        Wq[i] = f2b(w);
    }
    for (int i = idx; i < 256 * 256; i += stride) Wa[i] = f2b(attn_w[i]);
    for (int i = idx; i < C_ * V_; i += stride) {
        int c = i / V_, v = i - c * V_;
        int j2 = c & ~1;
        float ang = (float)v * expf(-logf(10000.0f) * (float)j2 / (float)C_);
        pe[i] = (c & 1) ? cosf(ang) : sinf(ang);
    }
    for (int i = idx; i < NCOPY * 512; i += stride) bins[i] = 0.f;
}

// ---------------- data_bn stats: one kernel, lane = fixed joint ----------------
__global__ __launch_bounds__(1024) void dbn_kernel(const float* __restrict__ x,
                                                   const float* __restrict__ gamma,
                                                   const float* __restrict__ beta,
                                                   float* __restrict__ a_scale,
                                                   float* __restrict__ a_shift) {
    __shared__ float pgS[32][25], pgQ[32][25];
    int c = blockIdx.x;
    int tid = threadIdx.x, g = tid >> 5, l = tid & 31;
    float s = 0.f, s2 = 0.f;
    if (l < 25) {
        const float* base = x + (size_t)g * CTV + c * TV + l;
        #pragma unroll 8
        for (int t = 0; t < 128; ++t) {
            float v = base[t * 25];
            s += v; s2 += v * v;
        }
        pgS[g][l] = s; pgQ[g][l] = s2;
    }
    __syncthreads();
    if (tid < 25) {
        float S = 0.f, Q = 0.f;
        #pragma unroll
        for (int g2 = 0; g2 < 32; ++g2) { S += pgS[g2][tid]; Q += pgQ[g2][tid]; }
        float inv = 1.0f / 4096.0f;
        float mean = S * inv, var = Q * inv - mean * mean;
        int f = c * 25 + tid;
        float sc = rsqrtf(var + EPS_) * gamma[f];
        a_scale[f] = sc;
        a_shift[f] = beta[f] - mean * sc;
    }
}

// ---------------- bias2 = Ws*a_shift + b_s ; peproj = Ws*pe + b_s ----------------
__global__ void mkbias_kernel(const ushort* __restrict__ Wq,
                              const float* __restrict__ qkv_b,
                              const float* __restrict__ a_shift,
                              const float* __restrict__ pe,
                              float* __restrict__ bias2, float* __restrict__ peproj) {
    int id = blockIdx.x * 256 + threadIdx.x;
    if (id < 11200) {
        int o = id / 25, v = id - o * 25;
        float acc = qkv_b[o] * (o < 64 ? S_Q : 1.f);
        for (int c = 0; c < 256; ++c)
            acc = fmaf(b2f(Wq[o * 256 + c]), a_shift[c * 25 + v], acc);
        bias2[id] = acc;
    } else if (id < 14400) {
        int id2 = id - 11200;
        int r = id2 / 25, v = id2 - r * 25;
        float acc = qkv_b[r] * (r < 64 ? S_Q : 1.f);
        for (int c = 0; c < 256; ++c)
            acc = fmaf(b2f(Wq[r * 256 + c]), pe[c * 25 + v], acc);
        peproj[id2] = acc;
    }
}

// ---------------- fused per-token kernel ----------------
__global__ __launch_bounds__(512, 4) void fused_kernel(
        const float* __restrict__ x,
        const ushort* __restrict__ Wq,
        const float* __restrict__ bias2, const float* __restrict__ peproj,
        const float* __restrict__ a_scale,
        const ushort* __restrict__ Wa, const float* __restrict__ attn_b,
        float* __restrict__ out, float* __restrict__ bins) {
    // Regions: X [0,16896) Braw -> qkvV(swz 16384); Y [16896,33792) Bxn -> aT;
    //          Z [33792,54272) qkvT(swz 20480) -> pbuf [8][32][40]
    __shared__ __align__(16) char smem[54272];
    ushort* Braw = (ushort*)smem;
    ushort* Bxn  = (ushort*)(smem + 16896);
    ushort* qkvT = (ushort*)(smem + 33792);
    ushort* qkvV = (ushort*)smem;
    ushort* aT   = (ushort*)(smem + 16896);
    ushort* pbuf = (ushort*)(smem + 33792);

    int n = blockIdx.x >> 7, t = blockIdx.x & 127;
    int tid = threadIdx.x, wave = tid >> 6, lane = tid & 63;
    int lr = lane & 15, lg = lane >> 4;
    const float* xp = x + (size_t)n * CTV + t * V_;
    float* outp = out + (size_t)n * CTV + t * V_;
    float* mybins = bins + (blockIdx.x & (NCOPY - 1)) * 512;
    const f32x4 zacc = {0.f, 0.f, 0.f, 0.f};
    const bf16x8 zero8 = {0, 0, 0, 0, 0, 0, 0, 0};

    // ---- stage raw + scaled (shift folded into bias2) ----
    for (int i = tid; i < 6400; i += 512) {
        int c = i / 25, v = i - c * 25;
        float xv = xp[c * TV + v];
        int off = v * 264 + c;
        Braw[off] = f2b(xv);
        Bxn[off]  = f2b(xv * a_scale[i]);
    }
    for (int i = tid; i < 1792; i += 512) {   // zero rows 25..31
        int v = 25 + (i >> 8), c = i & 255;
        int off = v * 264 + c;
        Braw[off] = 0; Bxn[off] = 0;
    }
    __syncthreads();   // B1

    // ---- pq/pk tile (1 per wave), full K, reads Braw ----
    {
        const ushort* Arow = Wq + (wave * 16 + lr) * 256;
        f32x4 a0 = zacc, a1 = zacc;
        #pragma unroll
        for (int kk = 0; kk < 8; ++kk) {
            int k0 = kk * 32 + lg * 8;
            bf16x8 a  = LD8(Arow + k0);
            bf16x8 b0 = LD8(Braw + lr * 264 + k0);
            bf16x8 b1 = LD8(Braw + (16 + lr) * 264 + k0);
            a0 = MFMA16(a, b0, a0);
            a1 = MFMA16(a, b1, a1);
        }
        #pragma unroll
        for (int i2 = 0; i2 < 4; ++i2) {
            int r = wave * 16 + lg * 4 + i2;       // 0..127
            qkvT[qtswz(lr, 192 + r)] = f2b(a0[i2] + peproj[r * 25 + lr]);
            qkvT[qtswz(16 + lr, 192 + r)] =
                (lr < 9) ? f2b(a1[i2] + peproj[r * 25 + 16 + lr]) : (ushort)0;
        }
    }
    __syncthreads();   // B1.5: Braw reads done -> qkvV may overwrite region X

    // ---- q/k/g/v tiles: kk-outer, shared B fragments across the wave's tiles ----
    {
        int myTiles = (wave < 4) ? 4 : 3;   // tiles mt = wave + tt*8, mt < 28
        f32x4 acc[4][2];
        #pragma unroll
        for (int i = 0; i < 4; ++i) { acc[i][0] = zacc; acc[i][1] = zacc; }
        #pragma unroll
        for (int kk = 0; kk < 8; ++kk) {
            int k0 = kk * 32 + lg * 8;
            bf16x8 b0 = LD8(Bxn + lr * 264 + k0);
            bf16x8 b1 = LD8(Bxn + (16 + lr) * 264 + k0);
            #pragma unroll
            for (int tt = 0; tt < 4; ++tt) {
                if (tt < myTiles) {
                    int mt = wave + tt * 8;
                    bf16x8 a = LD8(Wq + (mt * 16 + lr) * 256 + k0);
                    acc[tt][0] = MFMA16(a, b0, acc[tt][0]);
                    acc[tt][1] = MFMA16(a, b1, acc[tt][1]);
                }
            }
        }
        #pragma unroll
        for (int tt = 0; tt < 4; ++tt) {
            if (tt < myTiles) {
                int mt = wave + tt * 8;
                #pragma unroll
                for (int i2 = 0; i2 < 4; ++i2) {
                    int o = mt * 16 + lg * 4 + i2;
                    float v0 = acc[tt][0][i2] + bias2[o * 25 + lr];
                    float v1 = acc[tt][1][i2] + ((lr < 9) ? bias2[o * 25 + 16 + lr] : 0.f);
                    if (mt < 12) {
                        qkvT[qtswz(lr, o)] = f2b(v0);
                        qkvT[qtswz(16 + lr, o)] = (lr < 9) ? f2b(v1) : (ushort)0;
                    } else {
                        int e = o - 192;
                        qkvV[qvswz(e, lr)] = f2b(v0);
                        qkvV[qvswz(e, 16 + lr)] = (lr < 9) ? f2b(v1) : (ushort)0;
                    }
                }
            }
        }
    }
    __syncthreads();   // B2: all qkvT/qkvV writes + Bxn reads done

    // ---- weights phase (wave = head h) ----
    int h = wave;
    float qs = 0.f;
    if (lane < 8) {
        #pragma unroll
        for (int v = 0; v < 25; ++v)
            qs += b2f(qkvT[v * 320 + ((h ^ (v & 7)) << 3) + lane]);
        qs *= (1.f / 25.f);
    }
    float m[8];
    #pragma unroll
    for (int d = 0; d < 8; ++d) m[d] = __shfl(qs, d, 64);
    float u1a = 0.f, u1b = 0.f, u2a = 0.f, u2b = 0.f;
    {
        int ra = lr, rb = 16 + lr;
        int ka = ((8 + h) ^ (ra & 7)) << 3, kb = ((8 + h) ^ (rb & 7)) << 3;
        int ga = ((16 + h) ^ (ra & 7)) << 3, gb = ((16 + h) ^ (rb & 7)) << 3;
        #pragma unroll
        for (int d = 0; d < 8; ++d) {
            u1a = fmaf(m[d], b2f(qkvT[ra * 320 + ka + d]), u1a);
            u1b = fmaf(m[d], b2f(qkvT[rb * 320 + kb + d]), u1b);
            u2a = fmaf(m[d], b2f(qkvT[ra * 320 + ga + d]), u2a);
            u2b = fmaf(m[d], b2f(qkvT[rb * 320 + gb + d]), u2b);
        }
    }
    bf16x8 aP1[2], aP2[2], bP1[2], bP2[2];
    #pragma unroll
    for (int mi = 0; mi < 2; ++mi) {
        int row = mi * 16 + lr, sx = row & 7;
        const ushort* rp = qkvT + row * 320;
        aP1[mi] = (lg == 0) ? LD8(rp + ((h ^ sx) << 3))
                : (lg == 1) ? LD8(rp + (((24 + h) ^ sx) << 3)) : zero8;
        aP2[mi] = (lg == 0) ? LD8(rp + (((24 + h) ^ sx) << 3)) : zero8;
        bP1[mi] = (lg == 0) ? LD8(rp + (((8 + h) ^ sx) << 3))
                : (lg == 1) ? LD8(rp + (((32 + h) ^ sx) << 3)) : zero8;
        bP2[mi] = (lg == 0) ? LD8(rp + (((32 + h) ^ sx) << 3)) : zero8;
    }
    f32x4 p1[2][2], p2[2][2];
    #pragma unroll
    for (int mi = 0; mi < 2; ++mi)
        #pragma unroll
        for (int ni = 0; ni < 2; ++ni) {
            p1[mi][ni] = MFMA16(aP1[mi], bP1[ni], zacc);
            p2[mi][ni] = MFMA16(aP2[mi], bP2[ni], zacc);
        }
    __syncthreads();   // B3: qkvT reads done -> pbuf may overwrite region Z

    // ---- pbuf[h][v][w] = tanh(P1-u1) + tanh(P2+u2) (wave-local region) ----
    #pragma unroll
    for (int mi = 0; mi < 2; ++mi)
        #pragma unroll
        for (int ni = 0; ni < 2; ++ni) {
            float uu1 = ni ? u1b : u1a, uu2 = ni ? u2b : u2a;
            int w = ni * 16 + lr;
            #pragma unroll
            for (int i2 = 0; i2 < 4; ++i2) {
                int v = mi * 16 + lg * 4 + i2;
                float tw = tanh_fast(p1[mi][ni][i2] - uu1) + tanh_fast(p2[mi][ni][i2] + uu2);
                pbuf[(h * 32 + v) * 40 + w] = (w < 25) ? f2b(tw) : (ushort)0;
            }
        }

    // ---- attn^T: A = weights (M=v,K=w), B = V^T (K=w,N=e); wave-local ----
    {
        bf16x8 aw[2], bv[2];
        #pragma unroll
        for (int mi = 0; mi < 2; ++mi)
            aw[mi] = LD8(pbuf + (h * 32 + mi * 16 + lr) * 40 + lg * 8);
        #pragma unroll
        for (int ni = 0; ni < 2; ++ni) {
            int e = h * 32 + ni * 16 + lr;
            bv[ni] = LD8(qkvV + e * 32 + ((lg ^ (e & 3)) << 3));
        }
        f32x4 at_[2][2];
        #pragma unroll
        for (int mi = 0; mi < 2; ++mi)
            #pragma unroll
            for (int ni = 0; ni < 2; ++ni)
                at_[mi][ni] = MFMA16(aw[mi], bv[ni], zacc);
        // aT (region Y, dead since B2) : aT[v][e]
        #pragma unroll
        for (int mi = 0; mi < 2; ++mi)
            #pragma unroll
            for (int ni = 0; ni < 2; ++ni)
                #pragma unroll
                for (int i2 = 0; i2 < 4; ++i2) {
                    int v = mi * 16 + lg * 4 + i2;
                    int e = h * 32 + ni * 16 + lr;
                    aT[v * 264 + e] = (v < 25) ? f2b(at_[mi][ni][i2]) : (ushort)0;
                }
    }
    __syncthreads();   // B5: aT complete

    // ---- GEMM2 + direct store + bn2 partial sums (spread atomics) ----
    #pragma unroll
    for (int tt = 0; tt < 2; ++tt) {
        int o0 = (wave + tt * 8) * 16;
        const ushort* Arow = Wa + (o0 + lr) * 256;
        f32x4 a0 = zacc, a1 = zacc;
        #pragma unroll
        for (int kk = 0; kk < 8; ++kk) {
            int k0 = kk * 32 + lg * 8;
            bf16x8 a  = LD8(Arow + k0);
            bf16x8 b0 = LD8(aT + lr * 264 + k0);
            bf16x8 b1 = LD8(aT + (16 + lr) * 264 + k0);
            a0 = MFMA16(a, b0, a0);
            a1 = MFMA16(a, b1, a1);
        }
        #pragma unroll
        for (int i2 = 0; i2 < 4; ++i2) {
            int o = o0 + lg * 4 + i2;
            float bias = attn_b[o];
            float v0 = a0[i2] + bias + xp[o * TV + lr];
            outp[o * TV + lr] = v0;
            float v1 = 0.f;
            if (lr < 9) {
                v1 = a1[i2] + bias + xp[o * TV + 16 + lr];
                outp[o * TV + 16 + lr] = v1;
            }
            float cs = v0 + v1, cq = v0 * v0 + v1 * v1;
            #pragma unroll
            for (int mm = 1; mm < 16; mm <<= 1) {
                cs += __shfl_xor(cs, mm, 64);
                cq += __shfl_xor(cq, mm, 64);
            }
            if (lr == 0) {
                atomicAdd(&mybins[o], cs);
                atomicAdd(&mybins[256 + o], cq);
            }
        }
    }
}

// ---------------- bn2 final: fold NCOPY copies -> scale/shift ----------------
__global__ void bn2_final_kernel(const float* __restrict__ bins,
                                 const float* __restrict__ gamma,
                                 const float* __restrict__ beta,
                                 float* __restrict__ scale,
                                 float* __restrict__ shift) {
    int c = threadIdx.x;
    float s = 0.f, q = 0.f;
    for (int cp = 0; cp < NCOPY; ++cp) {
        s += bins[cp * 512 + c];
        q += bins[cp * 512 + 256 + c];
    }
    float inv = 1.0f / (float)(N_ * TV);
    float mean = s * inv;
    float var = q * inv - mean * mean;
    float sc = rsqrtf(var + EPS_) * gamma[c];
    scale[c] = sc;
    shift[c] = beta[c] - mean * sc;
}

__global__ void bn2_apply_kernel(float4* __restrict__ y,
                                 const float* __restrict__ scale,
                                 const float* __restrict__ shift) {
    const int total4 = N_ * CTV / 4;
    for (int i = blockIdx.x * blockDim.x + threadIdx.x; i < total4;
         i += gridDim.x * blockDim.x) {
        int c = (i / (TV / 4)) & 255;
        float4 v = y[i];
        float sc = scale[c], sh = shift[c];
        v.x = fmaxf(fmaf(v.x, sc, sh), 0.f);
        v.y = fmaxf(fmaf(v.y, sc, sh), 0.f);
        v.z = fmaxf(fmaf(v.z, sc, sh), 0.f);
        v.w = fmaxf(fmaf(v.w, sc, sh), 0.f);
        y[i] = v;
    }
}

extern "C" void kernel_launch(void* const* d_in, const int* in_sizes, int n_in,
                              void* d_out, int out_size, void* d_ws, size_t ws_size,
                              hipStream_t stream) {
    const float* x      = (const float*)d_in[0];
    const float* qkv_w  = (const float*)d_in[1];
    const float* qkv_b  = (const float*)d_in[2];
    const float* attn_w = (const float*)d_in[3];
    const float* attn_b = (const float*)d_in[4];
    const float* dbn_g  = (const float*)d_in[5];
    const float* dbn_b  = (const float*)d_in[6];
    const float* bn_g   = (const float*)d_in[7];
    const float* bn_b   = (const float*)d_in[8];
    float* out = (float*)d_out;

    char* ws = (char*)d_ws;
    ushort* Wq      = (ushort*)ws;                 // 229376 B
    ushort* Wa      = (ushort*)(ws + 229376);      // 131072 B
    float*  pe      = (float*)(ws + 360448);       // 25600 B
    float*  a_scale = (float*)(ws + 386048);       // 25600 B
    float*  a_shift = (float*)(ws + 411648);       // 25600 B
    float*  bias2   = (float*)(ws + 437248);       // 44800 B
    float*  peproj  = (float*)(ws + 482048);       // 12800 B
    float*  bins    = (float*)(ws + 494848);       // 131072 B (64 copies x 512)
    float*  bn2_sc  = (float*)(ws + 625920);       // 1024 B
    float*  bn2_sh  = (float*)(ws + 626944);       // 1024 B

    prep_kernel<<<256, 256, 0, stream>>>(qkv_w, attn_w, Wq, Wa, pe, bins);
    dbn_kernel<<<C_, 1024, 0, stream>>>(x, dbn_g, dbn_b, a_scale, a_shift);
    mkbias_kernel<<<57, 256, 0, stream>>>(Wq, qkv_b, a_shift, pe, bias2, peproj);
    fused_kernel<<<N_ * T_, 512, 0, stream>>>(x, Wq, bias2, peproj, a_scale,
                                              Wa, attn_b, out, bins);
    bn2_final_kernel<<<1, 256, 0, stream>>>(bins, bn_g, bn_b, bn2_sc, bn2_sh);
    bn2_apply_kernel<<<4096, 256, 0, stream>>>((float4*)out, bn2_sc, bn2_sh);
}